// Round 9
// baseline (197.644 us; speedup 1.0000x reference)
//
#include <hip/hip_runtime.h>
#include <math.h>

#define N_NODES 8192
#define D_FEAT  512
#define DEG     16
#define E_EDGES (N_NODES * DEG)
#define FEAT_W  576      // 544 used (8*(64+4)) + 32 zero-pad for K%64==0
#define FEAT_USED 544
#define OUT_W   512
#define QKV_W   1664     // 512 q | 512 k | 512 v | 24 qv | 104 pad  (13*128)

typedef unsigned short u16;
typedef __attribute__((ext_vector_type(8))) short short8;   // 8 bf16 for MFMA
typedef __attribute__((ext_vector_type(8))) unsigned short us8;
typedef __attribute__((ext_vector_type(4))) float f32x4;

// ---- bf16 helpers (RNE) ----------------------------------------------------
__device__ __forceinline__ u16 f2bf(float f) {
    union { float f; unsigned u; } c; c.f = f;
    unsigned u = c.u;
    unsigned r = u + 0x7FFFu + ((u >> 16) & 1u);
    return (u16)(r >> 16);
}
__device__ __forceinline__ float bf2f(u16 h) {
    union { unsigned u; float f; } c; c.u = ((unsigned)h) << 16;
    return c.f;
}

// ---- async global->LDS 16B (lds dest = wave-uniform base + lane*16) --------
__device__ __forceinline__ void async16(const void* g, void* l) {
    __builtin_amdgcn_global_load_lds(
        (const __attribute__((address_space(1))) void*)g,
        (__attribute__((address_space(3))) void*)l, 16, 0, 0);
}

// pack 8 fp32 (from two float4) -> 8 bf16 with scale
__device__ __forceinline__ us8 pack8(float4 a, float4 b, float s) {
    us8 w;
    w[0] = f2bf(a.x * s); w[1] = f2bf(a.y * s);
    w[2] = f2bf(a.z * s); w[3] = f2bf(a.w * s);
    w[4] = f2bf(b.x * s); w[5] = f2bf(b.y * s);
    w[6] = f2bf(b.z * s); w[7] = f2bf(b.w * s);
    return w;
}

// ---------------------------------------------------------------------------
// qkv GEMM, self-staging from fp32: qkv[8192,1664] = x[8192,512] * B^T where
// B rows are Wq*0.125 | Wk | Wv | Wqv | 0-pad, converted bf16 during staging.
// BK=64, 128x128 tiles, 4 waves. Grid 832 = 64 Mtiles x 13 Ntiles,
// XCD-swizzled (flat%8 keys XCD; all N-tiles of an M-tile share an XCD).
// LDS [128][64] u16 per matrix, 16B-chunk XOR-swizzle by (row&7) applied at
// the LDS *write* address (ds_write path controls its own dest).
// ---------------------------------------------------------------------------
__global__ __launch_bounds__(256) void gemm_qkv(
    const float* __restrict__ x,
    const float* __restrict__ Wq, const float* __restrict__ Wk,
    const float* __restrict__ Wv, const float* __restrict__ Wqv,
    u16* __restrict__ qkv)
{
    __shared__ u16 smem[128 * 64 * 2];   // 32 KB
    u16* sA = smem;
    u16* sB = smem + 128 * 64;

    const int tid = threadIdx.x;
    const int flat = blockIdx.x;
    const int xcd = flat & 7;
    const int rr  = flat >> 3;                  // 0..103
    const int bm  = (xcd + 8 * (rr / 13)) * 128;
    const int bn  = (rr % 13) * 128;

    const int wave = tid >> 6;
    const int lane = tid & 63;
    const int wr   = (wave >> 1) * 64;
    const int wc   = (wave & 1) * 64;
    const int lrow = lane & 15;
    const int quad = lane >> 4;

    f32x4 acc[4][4];
    #pragma unroll
    for (int i = 0; i < 4; ++i)
        #pragma unroll
        for (int j = 0; j < 4; ++j) {
            f32x4 z = {0.f, 0.f, 0.f, 0.f};
            acc[i][j] = z;
        }

    for (int k0 = 0; k0 < 512; k0 += 64) {
        // Stage: 1024 16B chunks per matrix, 4 per thread. Chunk slot lin =
        // row*8 + cs holds k-chunk cu = cs ^ (row&7) (elements cu*8..cu*8+7).
        #pragma unroll
        for (int i = 0; i < 4; ++i) {
            const int lin = i * 256 + tid;
            const int row = lin >> 3;
            const int seg = ((lin & 7) ^ (row & 7)) << 3;   // source k offset
            // A from x fp32
            {
                const float* s = x + (size_t)(bm + row) * 512 + k0 + seg;
                const float4 a0 = *(const float4*)(s);
                const float4 a1 = *(const float4*)(s + 4);
                *(us8*)&sA[lin << 3] = pack8(a0, a1, 1.f);
            }
            // B from Wq/Wk/Wv/Wqv fp32 (row-dependent source; zero pad rows)
            {
                const int br = bn + row;
                const float* s = nullptr; float sc = 1.f;
                if (br < 512)       { s = Wq + (size_t)br * 512; sc = 0.125f; }
                else if (br < 1024) { s = Wk + (size_t)(br - 512) * 512; }
                else if (br < 1536) { s = Wv + (size_t)(br - 1024) * 512; }
                else if (br < 1560) { s = Wqv + (size_t)(br - 1536) * 512; }
                us8 w = {0, 0, 0, 0, 0, 0, 0, 0};
                if (s) {
                    const float4 b0 = *(const float4*)(s + k0 + seg);
                    const float4 b1 = *(const float4*)(s + k0 + seg + 4);
                    w = pack8(b0, b1, sc);
                }
                *(us8*)&sB[lin << 3] = w;
            }
        }
        __syncthreads();

        #pragma unroll
        for (int ko = 0; ko < 64; ko += 32) {
            const int cbase = ko >> 3;
            short8 a_h[4], b_h[4];
            #pragma unroll
            for (int t = 0; t < 4; ++t) {
                const int ra = wr + t * 16 + lrow;
                const int rb = wc + t * 16 + lrow;
                a_h[t] = *(const short8*)&sA[ra * 64 + (((cbase + quad) ^ (ra & 7)) << 3)];
                b_h[t] = *(const short8*)&sB[rb * 64 + (((cbase + quad) ^ (rb & 7)) << 3)];
            }
            #pragma unroll
            for (int mt = 0; mt < 4; ++mt)
                #pragma unroll
                for (int nt = 0; nt < 4; ++nt)
                    acc[mt][nt] = __builtin_amdgcn_mfma_f32_16x16x32_bf16(
                        a_h[mt], b_h[nt], acc[mt][nt], 0, 0, 0);
        }
        __syncthreads();
    }

    // C/D layout: col = lane&15, row = quad*4 + r
    #pragma unroll
    for (int nt = 0; nt < 4; ++nt) {
        const int col = bn + wc + nt * 16 + lrow;
        #pragma unroll
        for (int mt = 0; mt < 4; ++mt)
            #pragma unroll
            for (int r = 0; r < 4; ++r) {
                const int row = bm + wr + mt * 16 + quad * 4 + r;
                qkv[(size_t)row * QKV_W + col] = f2bf(acc[mt][nt][r]);
            }
    }
}

// ---------------------------------------------------------------------------
// Out GEMM: out[8192,512] = feat[8192,576](bf16) * Wout'^T + bout, where
// Wout' is Wout[512,544] fp32 zero-padded to 576, converted during staging.
// A staged via global_load_lds (bf16 source); B via ds_write (fp32 source).
// Grid 256 = 64 Mtiles x 4 Ntiles, XCD-swizzled.
// ---------------------------------------------------------------------------
__global__ __launch_bounds__(256) void gemm_out(
    const u16* __restrict__ feat, const float* __restrict__ Wout,
    const float* __restrict__ bout, float* __restrict__ out)
{
    __shared__ u16 smem[128 * 64 * 2];   // 32 KB
    u16* sA = smem;
    u16* sB = smem + 128 * 64;

    const int tid = threadIdx.x;
    const int flat = blockIdx.x;
    const int xcd = flat & 7;
    const int rr  = flat >> 3;                  // 0..31
    const int bm  = (xcd + 8 * (rr / 4)) * 128;
    const int bn  = (rr % 4) * 128;

    const int wave = tid >> 6;
    const int lane = tid & 63;
    const int wr   = (wave >> 1) * 64;
    const int wc   = (wave & 1) * 64;
    const int lrow = lane & 15;
    const int quad = lane >> 4;

    f32x4 acc[4][4];
    #pragma unroll
    for (int i = 0; i < 4; ++i)
        #pragma unroll
        for (int j = 0; j < 4; ++j) {
            f32x4 z = {0.f, 0.f, 0.f, 0.f};
            acc[i][j] = z;
        }

    for (int k0 = 0; k0 < FEAT_W; k0 += 64) {
        #pragma unroll
        for (int i = 0; i < 4; ++i) {
            const int lin = i * 256 + tid;
            const int row = lin >> 3;
            const int seg = ((lin & 7) ^ (row & 7)) << 3;
            // A: feat bf16 via async (source-side swizzle; dest = lane-linear)
            async16(feat + (size_t)(bm + row) * FEAT_W + k0 + seg, sA + (lin << 3));
            // B: Wout fp32 [512,544], zero for cols >= 544 (chunk-aligned)
            {
                const int col = k0 + seg;
                us8 w = {0, 0, 0, 0, 0, 0, 0, 0};
                if (col < FEAT_USED) {
                    const float* s = Wout + (size_t)(bn + row) * FEAT_USED + col;
                    const float4 b0 = *(const float4*)(s);
                    const float4 b1 = *(const float4*)(s + 4);
                    w = pack8(b0, b1, 1.f);
                }
                *(us8*)&sB[lin << 3] = w;
            }
        }
        __syncthreads();

        #pragma unroll
        for (int ko = 0; ko < 64; ko += 32) {
            const int cbase = ko >> 3;
            short8 a_h[4], b_h[4];
            #pragma unroll
            for (int t = 0; t < 4; ++t) {
                const int ra = wr + t * 16 + lrow;
                const int rb = wc + t * 16 + lrow;
                a_h[t] = *(const short8*)&sA[ra * 64 + (((cbase + quad) ^ (ra & 7)) << 3)];
                b_h[t] = *(const short8*)&sB[rb * 64 + (((cbase + quad) ^ (rb & 7)) << 3)];
            }
            #pragma unroll
            for (int mt = 0; mt < 4; ++mt)
                #pragma unroll
                for (int nt = 0; nt < 4; ++nt)
                    acc[mt][nt] = __builtin_amdgcn_mfma_f32_16x16x32_bf16(
                        a_h[mt], b_h[nt], acc[mt][nt], 0, 0, 0);
        }
        __syncthreads();
    }

    #pragma unroll
    for (int nt = 0; nt < 4; ++nt) {
        const int col = bn + wc + nt * 16 + lrow;
        const float bb = bout[col];
        #pragma unroll
        for (int mt = 0; mt < 4; ++mt)
            #pragma unroll
            for (int r = 0; r < 4; ++r) {
                const int row = bm + wr + mt * 16 + quad * 4 + r;
                out[(size_t)row * OUT_W + col] = acc[mt][nt][r] + bb;
            }
    }
}

// ---------------------------------------------------------------------------
// Edge stage (round-5/7 proven config): ONE WAVE PER NODE, two-pass with LDS
// v-staging. lane = h*8+sub owns dims [lane*8, lane*8+8) of the 512-dim row.
// ---------------------------------------------------------------------------
#define EK_WAVES 2   // 16 KB LDS per wave; 32 KB/block
__global__ __launch_bounds__(EK_WAVES * 64) void edge_kernel(
    const u16* __restrict__ qkv,        // [N, 1664] bf16
    const int* __restrict__ col_index, const int* __restrict__ to_col,
    const float* __restrict__ att_bias, const float* __restrict__ dist,
    const float* __restrict__ pos, const float* __restrict__ col_pos,
    u16* __restrict__ feat)             // [N, 576] bf16 (544 used)
{
    __shared__ u16 vbuf[EK_WAVES * DEG * 512];

    const int wave = threadIdx.x >> 6;
    const int lane = threadIdx.x & 63;
    const int n = blockIdx.x * EK_WAVES + wave;
    const int h = lane >> 3;
    const int sub = lane & 7;

    const size_t qbase = (size_t)n * QKV_W;
    const int hoff = lane * 8;            // == h*64 + sub*8

    float qf[8];
    {
        const us8 qu = *(const us8*)(qkv + qbase + hoff);
        #pragma unroll
        for (int i = 0; i < 8; ++i) qf[i] = bf2f(qu[i]);
    }
    float qv0, qv1, qv2;
    {
        const float qvl = bf2f(qkv[qbase + 1536 + (lane < 24 ? lane : 0)]);
        qv0 = __shfl(qvl, h * 3 + 0);
        qv1 = __shfl(qvl, h * 3 + 1);
        qv2 = __shfl(qvl, h * 3 + 2);
    }
    const float px = pos[3 * n + 0], py = pos[3 * n + 1], pz = pos[3 * n + 2];

    const int j16 = lane & 15;
    const int e0  = n * DEG + j16;
    const int c_l  = col_index[e0];
    const int cc_l = to_col[c_l];
    const float d_l = dist[e0];
    const float invd_l = (d_l == 0.f) ? 0.f : (1.f / d_l);
    const float rx_l = col_pos[3 * c_l + 0] - px;
    const float ry_l = col_pos[3 * c_l + 1] - py;
    const float rz_l = col_pos[3 * c_l + 2] - pz;

    const float b0 = att_bias[(size_t)h * E_EDGES + n * DEG + sub * 2 + 0];
    const float b1 = att_bias[(size_t)h * E_EDGES + n * DEG + sub * 2 + 1];

    float logit[DEG];
    u16* vb = &vbuf[wave * DEG * 512];
    #pragma unroll
    for (int j = 0; j < DEG; ++j) {
        const int cc = __shfl(cc_l, j);
        const u16* rowp = qkv + (size_t)cc * QKV_W + hoff;
        async16(rowp + 1024, vb + j * 512);          // v row -> LDS
        const us8 ku = *(const us8*)(rowp + 512);    // k row -> regs
        float dot = 0.f;
        #pragma unroll
        for (int i = 0; i < 8; ++i) dot += qf[i] * bf2f(ku[i]);
        dot += __shfl_xor(dot, 1, 8);
        dot += __shfl_xor(dot, 2, 8);
        dot += __shfl_xor(dot, 4, 8);
        const float invd = __shfl(invd_l, j);
        const float ang = qv0 * __shfl(rx_l, j) + qv1 * __shfl(ry_l, j)
                        + qv2 * __shfl(rz_l, j);
        const float bj = __shfl((j & 1) ? b1 : b0, j >> 1, 8);
        logit[j] = dot + bj + ang * invd;
    }

    float m = logit[0];
    #pragma unroll
    for (int j = 1; j < DEG; ++j) m = fmaxf(m, logit[j]);
    float s = 0.f;
    #pragma unroll
    for (int j = 0; j < DEG; ++j) { logit[j] = __expf(logit[j] - m); s += logit[j]; }
    const float inv_s = 1.f / s;

    __syncthreads();   // drain global_load_lds + make LDS visible

    float y[8] = {0.f, 0.f, 0.f, 0.f, 0.f, 0.f, 0.f, 0.f};
    float dx = 0.f, dy = 0.f, dz = 0.f, aid = 0.f;
    #pragma unroll
    for (int j = 0; j < DEG; ++j) {
        const float a = logit[j] * inv_s;
        const us8 vu = *(const us8*)&vb[j * 512 + hoff];
        #pragma unroll
        for (int i = 0; i < 8; ++i) y[i] += a * bf2f(vu[i]);
        const float na = a * __shfl(invd_l, j);
        dx += na * __shfl(rx_l, j);
        dy += na * __shfl(ry_l, j);
        dz += na * __shfl(rz_l, j);
        aid += na;
    }

    u16* f = feat + (size_t)n * FEAT_W + h * 68;
    ushort4 o0, o1;
    o0.x = f2bf(y[0]); o0.y = f2bf(y[1]); o0.z = f2bf(y[2]); o0.w = f2bf(y[3]);
    o1.x = f2bf(y[4]); o1.y = f2bf(y[5]); o1.z = f2bf(y[6]); o1.w = f2bf(y[7]);
    *(ushort4*)(f + sub * 8 + 0) = o0;
    *(ushort4*)(f + sub * 8 + 4) = o1;
    if (sub == 0) {
        const float nrm = sqrtf(dx * dx + dy * dy + dz * dz);
        const float rn = 1.f / fmaxf(nrm, 1e-12f);
        ushort4 ex;
        ex.x = f2bf(dx * rn); ex.y = f2bf(dy * rn);
        ex.z = f2bf(dz * rn); ex.w = f2bf(aid);
        *(ushort4*)(f + 64) = ex;
    }
}

// ---------------------------------------------------------------------------
extern "C" void kernel_launch(void* const* d_in, const int* in_sizes, int n_in,
                              void* d_out, int out_size, void* d_ws, size_t ws_size,
                              hipStream_t stream)
{
    const float* x         = (const float*)d_in[0];
    const int*   col_index = (const int*)d_in[2];
    const int*   to_col    = (const int*)d_in[3];
    const float* att_bias  = (const float*)d_in[4];
    const float* dist      = (const float*)d_in[5];
    const float* pos       = (const float*)d_in[6];
    const float* col_pos   = (const float*)d_in[7];
    const float* Wq        = (const float*)d_in[8];
    const float* Wqv       = (const float*)d_in[9];
    const float* Wk        = (const float*)d_in[10];
    const float* Wv        = (const float*)d_in[11];
    const float* Wout      = (const float*)d_in[12];
    const float* bout      = (const float*)d_in[13];
    float* out = (float*)d_out;

    // Workspace: qkv [8192,1664] bf16 (27,262,976 B) + feat [8192,576] bf16
    char* ws = (char*)d_ws;
    u16* qkv  = (u16*)(ws + 0);
    u16* feat = (u16*)(ws + 27262976);

    dim3 blk(256);

    // 1) qkv = x * [Wq*s|Wk|Wv|Wqv|0]^T, bf16 out, in-staging conversion
    hipLaunchKernelGGL(gemm_qkv, dim3(64 * 13), blk, 0, stream,
                       x, Wq, Wk, Wv, Wqv, qkv);

    // 2) edge: wave per node, two-pass + LDS v-staging
    hipLaunchKernelGGL(edge_kernel, dim3(N_NODES / EK_WAVES), dim3(EK_WAVES * 64),
                       0, stream,
                       qkv, col_index, to_col, att_bias, dist, pos, col_pos, feat);

    // 3) out = feat * Wout'^T + bout, in-staging conversion of Wout
    hipLaunchKernelGGL(gemm_out, dim3(64 * 4), blk, 0, stream,
                       feat, Wout, bout, out);
}